// Round 6
// baseline (181.913 us; speedup 1.0000x reference)
//
#include <hip/hip_runtime.h>
#include <hip/hip_bf16.h>

// SeqAttention: banded relative-position attention.
// out[b,i,:] = softmax_k( (q_i . key[i+k] + q_i . pe[:,k]) / 8 ) @ value[i+k,:], k in [0,1024)
//
// R6: break the __syncthreads vmcnt(0) drain. Staging = register prefetch
// (global_load_dwordx4 for tile t+1 issued before computing tile t) +
// ds_write_b128, with raw s_waitcnt lgkmcnt(0) + s_barrier (LDS-only fence;
// prefetch loads stay in flight across the barrier). Also: hw
// v_cvt_pk_bf16_f32 packing (guarded) and Q pre-scaled by 0.125*log2e.

typedef __attribute__((ext_vector_type(8))) short bf16x8;
typedef __attribute__((ext_vector_type(4))) short bf16x4;
typedef __attribute__((ext_vector_type(4))) float f32x4;

#define BHN   64
#define MQ    1024
#define DH    64
#define LS    1024
#define NKEY  2048
#define NTILE 17

#define SZ_PE  ((size_t)LS * DH * 2)              // 131072, swizzled bf16 [rel][d]
#define OFF_K  SZ_PE
#define SZ_K   ((size_t)BHN * NKEY * DH * 2)      // bf16, rows pre-swizzled
#define OFF_V  (OFF_K + SZ_K)
#define SZ_V   ((size_t)BHN * DH * NKEY * 2)      // bf16 V^T [bh][d][kappa-key]
#define WS_NEED (OFF_V + SZ_V)                    // ~33.7 MB

// 0.125 (1/sqrt(64)) * log2(e): folded into Q before bf16 cast
#define SCL_LOG2E 0.18033688011112042f

__device__ __forceinline__ short f2bf(float f) {
  unsigned u = __float_as_uint(f);
  u += 0x7FFFu + ((u >> 16) & 1u);                // RNE (inputs finite)
  return (short)(u >> 16);
}
__device__ __forceinline__ float bf2f(short s) {
  return __uint_as_float(((unsigned)(unsigned short)s) << 16);
}

#if defined(__has_builtin)
#if __has_builtin(__builtin_amdgcn_cvt_pk_bf16_f32)
#define HAVE_CVT_PK 1
#endif
#endif

// pack two f32 -> two bf16 (RNE) in one unsigned
__device__ __forceinline__ unsigned pk2(float a, float b) {
#ifdef HAVE_CVT_PK
  auto r = __builtin_amdgcn_cvt_pk_bf16_f32(a, b);
  unsigned u;
  __builtin_memcpy(&u, &r, 4);
  return u;
#else
  return (unsigned)(unsigned short)f2bf(a) | ((unsigned)(unsigned short)f2bf(b) << 16);
#endif
}
__device__ __forceinline__ bf16x4 mk4(unsigned a, unsigned b) {
  union { unsigned u[2]; bf16x4 v; } z;
  z.u[0] = a; z.u[1] = b;
  return z.v;
}
__device__ __forceinline__ bf16x8 mk8(unsigned a, unsigned b, unsigned c, unsigned d) {
  union { unsigned u[4]; bf16x8 v; } z;
  z.u[0] = a; z.u[1] = b; z.u[2] = c; z.u[3] = d;
  return z.v;
}

// LDS-only workgroup barrier: lgkmcnt(0) + s_barrier, NO vmcnt drain.
// 0xC07F = vmcnt(63) expcnt(7) lgkmcnt(0) on gfx9 encoding.
__device__ __forceinline__ void wg_barrier() {
  __asm__ volatile("" ::: "memory");
  __builtin_amdgcn_s_waitcnt(0xC07F);
  __builtin_amdgcn_s_barrier();
  __asm__ volatile("" ::: "memory");
}

// ---- fused prep: [0,256) PE, [256,2304) K, [2304,4352) V
__global__ __launch_bounds__(256)
void prep_fused(const float* __restrict__ pe, const float* __restrict__ K,
                const float* __restrict__ V, short* __restrict__ peT,
                short* __restrict__ Kb, short* __restrict__ Vb) {
  __shared__ short st[64 * 68];
  const int bx = blockIdx.x;
  if (bx < 256) {
    const int idx = bx * 256 + threadIdx.x;       // 65536
    const int rel = idx >> 6, d = idx & 63;
    peT[rel * 64 + (((d >> 3) ^ (rel & 7)) * 8) + (d & 7)] = f2bf(pe[d * LS + rel]);
  } else if (bx < 2304) {
    const size_t i = ((size_t)(bx - 256) * 256 + threadIdx.x) * 16;  // < 8,388,608
    const int row = (int)(i >> 6);
    const int c16 = (int)(i & 63);                // 0,16,32,48
    const float4 f0 = *(const float4*)(K + i);
    const float4 f1 = *(const float4*)(K + i + 4);
    const float4 f2 = *(const float4*)(K + i + 8);
    const float4 f3 = *(const float4*)(K + i + 12);
    const bf16x8 b0 = mk8(pk2(f0.x, f0.y), pk2(f0.z, f0.w), pk2(f1.x, f1.y), pk2(f1.z, f1.w));
    const bf16x8 b1 = mk8(pk2(f2.x, f2.y), pk2(f2.z, f2.w), pk2(f3.x, f3.y), pk2(f3.z, f3.w));
    const int s7 = row & 7;
    short* dst = Kb + (size_t)row * 64;
    *(bf16x8*)&dst[(((c16 >> 3))     ^ s7) * 8] = b0;
    *(bf16x8*)&dst[(((c16 >> 3) + 1) ^ s7) * 8] = b1;
  } else {
    const int b  = bx - 2304;                     // 0..2047
    const int bh = b >> 5, jt = b & 31;
    {  // phase 1: stage 64x64 tile [key][d], f32->bf16
      const int r = threadIdx.x >> 2, cb = (threadIdx.x & 3) * 16;
      const float* src = V + ((size_t)bh * NKEY + jt * 64 + r) * DH + cb;
#pragma unroll
      for (int c = 0; c < 16; c += 8) {
        float4 f0 = *(const float4*)(src + c);
        float4 f1 = *(const float4*)(src + c + 4);
        *(bf16x8*)&st[r * 68 + cb + c] =
            mk8(pk2(f0.x, f0.y), pk2(f0.z, f0.w), pk2(f1.x, f1.y), pk2(f1.z, f1.w));
      }
    }
    __syncthreads();
    {  // phase 2: transpose + kappa-permute, contiguous b128 writes
      const int d = threadIdx.x >> 2, kapb = (threadIdx.x & 3) * 16;
      __attribute__((aligned(16))) short tmp[16];
#pragma unroll
      for (int j = 0; j < 16; ++j) {
        const int kap = kapb + j;
        const int k   = (kap & 3) * 16 + (kap >> 2);
        tmp[j] = st[k * 68 + d];
      }
      short* dst = Vb + ((size_t)bh * DH + d) * NKEY + jt * 64 + kapb;
      *(bf16x8*)dst       = *(bf16x8*)&tmp[0];
      *(bf16x8*)(dst + 8) = *(bf16x8*)&tmp[8];
    }
  }
}

template <bool PRECONV>
__global__ __launch_bounds__(256, 4)
void seq_attn_kernel(const float* __restrict__ Qf, const float* __restrict__ Kf,
                     const float* __restrict__ Vf, const short* __restrict__ peT,
                     const short* __restrict__ Kb, const short* __restrict__ Vb,
                     float* __restrict__ Out) {
  // stride-64 + granule-XOR layouts: slot = (g ^ (row&7)), g = 16B granule.
  __shared__ short sK[64 * 64];        // [key][d-granules swizzled]         8KB
  __shared__ short sPE[2 * 64 * 64];   // 2-slot circular PE blocks          16KB
  __shared__ short sV[64 * 64];        // [d][kappa-granules swizzled]       8KB
  __shared__ short sPA[64 * 64];       // P, [row][kappa], b64-writable      8KB
  // total 40KB = 160KB / 4 blocks exactly

  const int tid  = threadIdx.x;
  const int w    = tid >> 6;
  const int lane = tid & 63;
  const int li   = lane & 15;
  const int quad = lane >> 4;
  // XCD-aware swizzle: 8 consecutive bh per XCD (Kb+Vb working set = 4MB = L2)
  const int linear = blockIdx.y * 16 + blockIdx.x;
  const int slot   = linear >> 3;
  const int bh     = (linear & 7) * 8 + (slot >> 4);
  const int i0     = (slot & 15) * 64;
  const int rbase  = w * 16 + quad * 4;

  // ---- Q A-fragments, pre-scaled by 0.125*log2(e) so exp2 args are bare adds
  bf16x8 aq[2];
  {
    const float* qp = Qf + (size_t)((bh * MQ + i0 + w * 16 + li) * DH) + quad * 8;
#pragma unroll
    for (int ks = 0; ks < 2; ++ks) {
      float4 f0 = *(const float4*)(qp + ks * 32);
      float4 f1 = *(const float4*)(qp + ks * 32 + 4);
      f0.x *= SCL_LOG2E; f0.y *= SCL_LOG2E; f0.z *= SCL_LOG2E; f0.w *= SCL_LOG2E;
      f1.x *= SCL_LOG2E; f1.y *= SCL_LOG2E; f1.z *= SCL_LOG2E; f1.w *= SCL_LOG2E;
      aq[ks] = mk8(pk2(f0.x, f0.y), pk2(f0.z, f0.w), pk2(f1.x, f1.y), pk2(f1.z, f1.w));
    }
  }

  float l_i[4] = {0.f, 0.f, 0.f, 0.f};
  f32x4 acco[4];
#pragma unroll
  for (int nt = 0; nt < 4; ++nt) acco[nt] = (f32x4){0.f, 0.f, 0.f, 0.f};

  f32x4 curPw[4];   // P over rel cols (4t-w+m)*16.., m=0..3 (per-wave window)
  f32x4 prevw3 = (f32x4){0.f, 0.f, 0.f, 0.f};

  // ---- t-invariant staging addresses (PRECONV pipeline)
  const int slot0 = w * 128 + lane;                 // it=0; it=1 adds 64 slots
  short* wrK  = sK  + slot0 * 8;
  short* wrV  = sV  + slot0 * 8;
  short* wrP0 = sPE + slot0 * 8;
  short* wrP1 = sPE + 4096 + slot0 * 8;
  const int vs0d = slot0 >> 3, vs0g = (slot0 & 7) ^ (vs0d & 7);
  const int s1 = slot0 + 64;
  const int vs1d = s1 >> 3,  vs1g = (s1 & 7) ^ (vs1d & 7);
  const short* gK  = Kb + ((size_t)bh * NKEY + i0) * 64 + slot0 * 8;
  const short* gV0 = Vb + ((size_t)bh * DH + vs0d) * NKEY + i0 + vs0g * 8;
  const short* gV1 = Vb + ((size_t)bh * DH + vs1d) * NKEY + i0 + vs1g * 8;
  const short* gPE = peT + slot0 * 8;

  bf16x8 kpf0, kpf1, vpf0, vpf1, ppf0, ppf1;
  if constexpr (PRECONV) {   // preamble: tile 0 + PE block 0
    kpf0 = *(const bf16x8*)gK;  kpf1 = *(const bf16x8*)(gK + 512);  gK += 4096;
    vpf0 = *(const bf16x8*)gV0; vpf1 = *(const bf16x8*)gV1;  gV0 += 64; gV1 += 64;
    ppf0 = *(const bf16x8*)gPE; ppf1 = *(const bf16x8*)(gPE + 512); gPE += 4096;
  }

  for (int t = 0; t < NTILE; ++t) {
    const int j0 = i0 + t * 64;
    wg_barrier();   // A: all LDS readers of tile t-1 done (lgkm only)

    if constexpr (PRECONV) {
      // stage tile t from prefetch regs (vmcnt waits attach here, a full
      // compute phase after the loads were issued)
      *(bf16x8*)wrK         = kpf0;
      *(bf16x8*)(wrK + 512) = kpf1;
      *(bf16x8*)wrV         = vpf0;
      *(bf16x8*)(wrV + 512) = vpf1;
      if (t < NTILE - 1) {
        short* wp = (t & 1) ? wrP1 : wrP0;
        *(bf16x8*)wp         = ppf0;
        *(bf16x8*)(wp + 512) = ppf1;
      }
      // issue loads for tile t+1 (stay in flight across the raw barrier)
      if (t + 1 < NTILE) {
        kpf0 = *(const bf16x8*)gK;  kpf1 = *(const bf16x8*)(gK + 512);  gK += 4096;
        vpf0 = *(const bf16x8*)gV0; vpf1 = *(const bf16x8*)gV1;  gV0 += 64; gV1 += 64;
      }
      if (t + 1 < NTILE - 1) {
        ppf0 = *(const bf16x8*)gPE; ppf1 = *(const bf16x8*)(gPE + 512); gPE += 4096;
      }
    } else {
      // ---- fallback: stage with in-kernel f32->bf16 conversion
      {
        const int srow = tid >> 2, l0 = tid & 3, sdb = l0 * 16;
        const float* src = Kf + (size_t)(bh * NKEY + j0 + srow) * DH + sdb;
        const float4 a0 = *(const float4*)(src + 0);
        const float4 a1 = *(const float4*)(src + 4);
        const float4 a2 = *(const float4*)(src + 8);
        const float4 a3 = *(const float4*)(src + 12);
        const bf16x8 b0 = mk8(pk2(a0.x, a0.y), pk2(a0.z, a0.w), pk2(a1.x, a1.y), pk2(a1.z, a1.w));
        const bf16x8 b1 = mk8(pk2(a2.x, a2.y), pk2(a2.z, a2.w), pk2(a3.x, a3.y), pk2(a3.z, a3.w));
        const int s7 = srow & 7;
        *(bf16x8*)&sK[srow * 64 + (((2 * l0)     ^ s7) * 8)] = b0;
        *(bf16x8*)&sK[srow * 64 + (((2 * l0 + 1) ^ s7) * 8)] = b1;
      }
      {
        const int vdb = (tid & 15) * 4, vkb = (tid >> 4) * 4;
        const float* src = Vf + (size_t)(bh * NKEY + j0 + vkb) * DH + vdb;
#pragma unroll
        for (int m = 0; m < 4; ++m) {             // key vkb+m
          const float4 rr = *(const float4*)(src + m * DH);
          const int k   = vkb + m;
          const int kap = (k & 15) * 4 + (k >> 4);
#pragma unroll
          for (int jj = 0; jj < 4; ++jj) {
            const int d = vdb + jj;
            const float fv = (jj == 0) ? rr.x : (jj == 1) ? rr.y : (jj == 2) ? rr.z : rr.w;
            sV[d * 64 + (((kap >> 3) ^ (d & 7)) * 8) + (kap & 7)] = f2bf(fv);
          }
        }
      }
      if (t < NTILE - 1) {
        const short* src = peT + (size_t)t * 64 * 64;   // already swizzled
        short* db = sPE + (size_t)(t & 1) * 4096;
        *(bf16x8*)&db[tid * 16]     = *(const bf16x8*)(src + tid * 16);
        *(bf16x8*)&db[tid * 16 + 8] = *(const bf16x8*)(src + tid * 16 + 8);
      }
    }
    wg_barrier();   // B: staging writes visible (lgkm only; prefetch in flight)

    // ---- curPw[m] = Q @ PE over rel col (4t-w+m)*16..+15 (per-wave window).
    // Out-of-range cols read defined-but-stale LDS; killed by the band mask.
#pragma unroll
    for (int m = 0; m < 4; ++m) {
      const int colIdx = 4 * t - w + m;
      const int base = ((colIdx >> 2) & 1) * 4096 + ((colIdx & 3) * 16 + li) * 64;
      f32x4 c = (f32x4){0.f, 0.f, 0.f, 0.f};
#pragma unroll
      for (int ks = 0; ks < 2; ++ks) {
        const int gs = (((ks * 4 + quad) ^ (li & 7)) * 8);
        const bf16x8 b = *(bf16x8*)&sPE[base + gs];
        c = __builtin_amdgcn_mfma_f32_16x16x32_bf16(aq[ks], b, c, 0, 0, 0);
      }
      curPw[m] = c;
    }

    // ---- S = Q @ K^T (scaled scores: Q was pre-scaled)
    f32x4 cs[4];
#pragma unroll
    for (int nt = 0; nt < 4; ++nt) {
      f32x4 c = (f32x4){0.f, 0.f, 0.f, 0.f};
#pragma unroll
      for (int ks = 0; ks < 2; ++ks) {
        const int gs = (((ks * 4 + quad) ^ (li & 7)) * 8);
        const bf16x8 b = *(bf16x8*)&sK[(nt * 16 + li) * 64 + gs];
        c = __builtin_amdgcn_mfma_f32_16x16x32_bf16(aq[ks], b, c, 0, 0, 0);
      }
      cs[nt] = c;
    }

    // ---- diagonal gather (3 packed shuffles per r) + no-max softmax
#pragma unroll
    for (int r = 0; r < 4; ++r) {
      const int e       = li - quad * 4 - r;          // in [-15, 15]
      const bool ge     = (e >= 0);
      const int srcLane = quad * 16 + (e & 15);
      const float shm = __shfl(prevw3[r], srcLane);
      const unsigned pk01 = pk2(curPw[0][r], curPw[1][r]);
      const unsigned pk23 = pk2(curPw[2][r], curPw[3][r]);
      const unsigned s01 = (unsigned)__shfl((int)pk01, srcLane);
      const unsigned s23 = (unsigned)__shfl((int)pk23, srcLane);
      const float sh0 = bf2f((short)(s01 & 0xffffu));
      const float sh1 = bf2f((short)(s01 >> 16));
      const float sh2 = bf2f((short)(s23 & 0xffffu));
      const float sh3 = bf2f((short)(s23 >> 16));
      const float pos0 = ge ? sh0 : shm;
      const float pos1 = ge ? sh1 : sh0;
      const float pos2 = ge ? sh2 : sh1;
      const float pos3 = ge ? sh3 : sh2;
      float p0 = __builtin_exp2f(cs[0][r] + pos0);
      float p1 = __builtin_exp2f(cs[1][r] + pos1);
      float p2 = __builtin_exp2f(cs[2][r] + pos2);
      float p3 = __builtin_exp2f(cs[3][r] + pos3);
      if (t == 0) {                 // valid iff dl>=0: nt>w || (nt==w && ge)
        p0 = (0 > w || (0 == w && ge)) ? p0 : 0.f;
        p1 = (1 > w || (1 == w && ge)) ? p1 : 0.f;
        p2 = (2 > w || (2 == w && ge)) ? p2 : 0.f;
        p3 = (3 > w || (3 == w && ge)) ? p3 : 0.f;
      } else if (t == NTILE - 1) {  // valid iff dl<0: nt<w || (nt==w && !ge)
        p0 = (0 < w || (0 == w && !ge)) ? p0 : 0.f;
        p1 = (1 < w || (1 == w && !ge)) ? p1 : 0.f;
        p2 = (2 < w || (2 == w && !ge)) ? p2 : 0.f;
        p3 = (3 < w || (3 == w && !ge)) ? p3 : 0.f;
      }
      l_i[r] += (p0 + p1) + (p2 + p3);
      // kappa-order store: lane li's keys nt*16+li -> kappa = 4*li + nt,
      // contiguous => one b64. Granule (li>>1) ^ (rowA&7), offset (li&1)*4.
      const int rowA = rbase + r;
      const bf16x4 pkv = mk4(pk2(p0, p1), pk2(p2, p3));
      *(bf16x4*)&sPA[rowA * 64 + (((li >> 1) ^ (rowA & 7)) * 8) + (li & 1) * 4] = pkv;
    }
    prevw3 = curPw[3];

    // ---- O += P @ V  (kappa-ordered contraction on both operands)
#pragma unroll
    for (int ks = 0; ks < 2; ++ks) {
      const int rowA = w * 16 + li;
      const bf16x8 ap =
          *(bf16x8*)&sPA[rowA * 64 + (((ks * 4 + quad) ^ (rowA & 7)) * 8)];
#pragma unroll
      for (int nt = 0; nt < 4; ++nt) {
        const int d  = nt * 16 + li;
        const int gs = (((ks * 4 + quad) ^ (d & 7)) * 8);
        const bf16x8 bv = *(bf16x8*)&sV[d * 64 + gs];
        acco[nt] = __builtin_amdgcn_mfma_f32_16x16x32_bf16(ap, bv, acco[nt], 0, 0, 0);
      }
    }
  }

  // ---- epilogue: reduce l across the 16 lanes holding each row, out = O / l
#pragma unroll
  for (int r = 0; r < 4; ++r) {
    float l = l_i[r];
    l += __shfl_xor(l, 1);
    l += __shfl_xor(l, 2);
    l += __shfl_xor(l, 4);
    l += __shfl_xor(l, 8);
    const float inv = 1.0f / l;
#pragma unroll
    for (int nt = 0; nt < 4; ++nt) {
      Out[(size_t)(bh * MQ + i0 + rbase + r) * DH + nt * 16 + li] = acco[nt][r] * inv;
    }
  }
}

extern "C" void kernel_launch(void* const* d_in, const int* in_sizes, int n_in,
                              void* d_out, int out_size, void* d_ws, size_t ws_size,
                              hipStream_t stream) {
  const float* q  = (const float*)d_in[0];  // [64,1024,64]
  const float* k  = (const float*)d_in[1];  // [64,2048,64]
  const float* v  = (const float*)d_in[2];  // [64,2048,64]
  const float* pe = (const float*)d_in[3];  // [1,64,1024]
  float* out = (float*)d_out;               // [64,1024,64] f32
  short* peT = (short*)d_ws;
  short* Kb  = (short*)((char*)d_ws + OFF_K);
  short* Vb  = (short*)((char*)d_ws + OFF_V);
  const bool preconv = ws_size >= WS_NEED;  // constant across calls: capture-safe

  dim3 grid(MQ / 64, BHN);
  if (preconv) {
    prep_fused<<<4352, 256, 0, stream>>>(pe, k, v, peT, Kb, Vb);
    seq_attn_kernel<true><<<grid, 256, 0, stream>>>(q, k, v, peT, Kb, Vb, out);
  } else {
    prep_fused<<<256, 256, 0, stream>>>(pe, k, v, peT, Kb, Vb);
    seq_attn_kernel<false><<<grid, 256, 0, stream>>>(q, k, v, peT, Kb, Vb, out);
  }
}

// Round 7
// 173.367 us; speedup vs baseline: 1.0493x; 1.0493x over previous
//
#include <hip/hip_runtime.h>
#include <hip/hip_bf16.h>

// SeqAttention: banded relative-position attention.
// out[b,i,:] = softmax_k( (q_i . key[i+k] + q_i . pe[:,k]) / 8 ) @ value[i+k,:], k in [0,1024)
//
// R7: R5 structure restored (global_load_lds staging + __syncthreads; R6's
// register prefetch spilled to scratch -> reverted). VALU cuts: raw
// v_exp_f32 via __builtin_amdgcn_exp2f, hw v_cvt_pk_bf16_f32 packing,
// Q pre-scaled by 0.125*log2e so exp2 args are bare adds.

typedef __attribute__((ext_vector_type(8))) short bf16x8;
typedef __attribute__((ext_vector_type(4))) short bf16x4;
typedef __attribute__((ext_vector_type(4))) float f32x4;

#define BHN   64
#define MQ    1024
#define DH    64
#define LS    1024
#define NKEY  2048
#define NTILE 17

#define SZ_PE  ((size_t)LS * DH * 2)              // 131072, swizzled bf16 [rel][d]
#define OFF_K  SZ_PE
#define SZ_K   ((size_t)BHN * NKEY * DH * 2)      // bf16, rows pre-swizzled
#define OFF_V  (OFF_K + SZ_K)
#define SZ_V   ((size_t)BHN * DH * NKEY * 2)      // bf16 V^T [bh][d][kappa-key]
#define WS_NEED (OFF_V + SZ_V)                    // ~33.7 MB

// 0.125 (1/sqrt(64)) * log2(e): folded into Q before bf16 cast
#define SCL_LOG2E 0.18033688011112042f

__device__ __forceinline__ short f2bf(float f) {
  unsigned u = __float_as_uint(f);
  u += 0x7FFFu + ((u >> 16) & 1u);                // RNE (inputs finite)
  return (short)(u >> 16);
}
__device__ __forceinline__ float bf2f(short s) {
  return __uint_as_float(((unsigned)(unsigned short)s) << 16);
}

#if defined(__has_builtin)
#if __has_builtin(__builtin_amdgcn_cvt_pk_bf16_f32)
#define HAVE_CVT_PK 1
#endif
#if __has_builtin(__builtin_amdgcn_exp2f)
#define HAVE_EXP2 1
#endif
#endif

__device__ __forceinline__ float fast_exp2(float x) {
#ifdef HAVE_EXP2
  return __builtin_amdgcn_exp2f(x);               // raw v_exp_f32 (args bounded)
#else
  return __builtin_exp2f(x);
#endif
}

// pack two f32 -> two bf16 (RNE) in one unsigned
__device__ __forceinline__ unsigned pk2(float a, float b) {
#ifdef HAVE_CVT_PK
  auto r = __builtin_amdgcn_cvt_pk_bf16_f32(a, b);
  unsigned u;
  __builtin_memcpy(&u, &r, 4);
  return u;
#else
  return (unsigned)(unsigned short)f2bf(a) | ((unsigned)(unsigned short)f2bf(b) << 16);
#endif
}
__device__ __forceinline__ bf16x4 mk4(unsigned a, unsigned b) {
  union { unsigned u[2]; bf16x4 v; } z;
  z.u[0] = a; z.u[1] = b;
  return z.v;
}
__device__ __forceinline__ bf16x8 mk8(unsigned a, unsigned b, unsigned c, unsigned d) {
  union { unsigned u[4]; bf16x8 v; } z;
  z.u[0] = a; z.u[1] = b; z.u[2] = c; z.u[3] = d;
  return z.v;
}
__device__ __forceinline__ void async_copy16(const void* g, void* l) {
  __builtin_amdgcn_global_load_lds((const __attribute__((address_space(1))) void*)g,
                                   (__attribute__((address_space(3))) void*)l, 16, 0, 0);
}

// ---- fused prep: [0,256) PE, [256,2304) K, [2304,4352) V
// PE: [1,D,L] f32 -> peT [rel][d] bf16, granule-swizzled by (rel&7)
// K : [bh*2048][64] f32 -> bf16 rows, granule-swizzled by (row&7)
// V : [bh][2048][64] f32 -> bf16 V^T [bh][64][2048], key dim kappa-permuted
//     per 64-block: kappa = (k&15)*4 + (k>>4)  (inverse k = (kap&3)*16 + (kap>>2))
__global__ __launch_bounds__(256)
void prep_fused(const float* __restrict__ pe, const float* __restrict__ K,
                const float* __restrict__ V, short* __restrict__ peT,
                short* __restrict__ Kb, short* __restrict__ Vb) {
  __shared__ short st[64 * 68];
  const int bx = blockIdx.x;
  if (bx < 256) {
    const int idx = bx * 256 + threadIdx.x;       // 65536
    const int rel = idx >> 6, d = idx & 63;
    peT[rel * 64 + (((d >> 3) ^ (rel & 7)) * 8) + (d & 7)] = f2bf(pe[d * LS + rel]);
  } else if (bx < 2304) {
    const size_t i = ((size_t)(bx - 256) * 256 + threadIdx.x) * 16;  // < 8,388,608
    const int row = (int)(i >> 6);
    const int c16 = (int)(i & 63);                // 0,16,32,48
    const float4 f0 = *(const float4*)(K + i);
    const float4 f1 = *(const float4*)(K + i + 4);
    const float4 f2 = *(const float4*)(K + i + 8);
    const float4 f3 = *(const float4*)(K + i + 12);
    const bf16x8 b0 = mk8(pk2(f0.x, f0.y), pk2(f0.z, f0.w), pk2(f1.x, f1.y), pk2(f1.z, f1.w));
    const bf16x8 b1 = mk8(pk2(f2.x, f2.y), pk2(f2.z, f2.w), pk2(f3.x, f3.y), pk2(f3.z, f3.w));
    const int s7 = row & 7;
    short* dst = Kb + (size_t)row * 64;
    *(bf16x8*)&dst[(((c16 >> 3))     ^ s7) * 8] = b0;
    *(bf16x8*)&dst[(((c16 >> 3) + 1) ^ s7) * 8] = b1;
  } else {
    const int b  = bx - 2304;                     // 0..2047
    const int bh = b >> 5, jt = b & 31;
    {  // phase 1: stage 64x64 tile [key][d], f32->bf16
      const int r = threadIdx.x >> 2, cb = (threadIdx.x & 3) * 16;
      const float* src = V + ((size_t)bh * NKEY + jt * 64 + r) * DH + cb;
#pragma unroll
      for (int c = 0; c < 16; c += 8) {
        float4 f0 = *(const float4*)(src + c);
        float4 f1 = *(const float4*)(src + c + 4);
        *(bf16x8*)&st[r * 68 + cb + c] =
            mk8(pk2(f0.x, f0.y), pk2(f0.z, f0.w), pk2(f1.x, f1.y), pk2(f1.z, f1.w));
      }
    }
    __syncthreads();
    {  // phase 2: transpose + kappa-permute, contiguous b128 writes
      const int d = threadIdx.x >> 2, kapb = (threadIdx.x & 3) * 16;
      __attribute__((aligned(16))) short tmp[16];
#pragma unroll
      for (int j = 0; j < 16; ++j) {
        const int kap = kapb + j;
        const int k   = (kap & 3) * 16 + (kap >> 2);
        tmp[j] = st[k * 68 + d];
      }
      short* dst = Vb + ((size_t)bh * DH + d) * NKEY + jt * 64 + kapb;
      *(bf16x8*)dst       = *(bf16x8*)&tmp[0];
      *(bf16x8*)(dst + 8) = *(bf16x8*)&tmp[8];
    }
  }
}

template <bool PRECONV>
__global__ __launch_bounds__(256, 4)
void seq_attn_kernel(const float* __restrict__ Qf, const float* __restrict__ Kf,
                     const float* __restrict__ Vf, const short* __restrict__ peT,
                     const short* __restrict__ Kb, const short* __restrict__ Vb,
                     float* __restrict__ Out) {
  // stride-64 + granule-XOR layouts: slot = (g ^ (row&7)), g = 16B granule.
  __shared__ short sK[64 * 64];        // [key][d-granules swizzled]         8KB
  __shared__ short sPE[2 * 64 * 64];   // 2-slot circular PE blocks          16KB
  __shared__ short sV[64 * 64];        // [d][kappa-granules swizzled]       8KB
  __shared__ short sPA[64 * 64];       // P, [row][kappa], b64-writable      8KB
  // total 40KB = 160KB / 4 blocks exactly

  const int tid  = threadIdx.x;
  const int w    = tid >> 6;
  const int lane = tid & 63;
  const int li   = lane & 15;
  const int quad = lane >> 4;
  // XCD-aware swizzle: 8 consecutive bh per XCD (Kb+Vb working set = 4MB = L2)
  const int linear = blockIdx.y * 16 + blockIdx.x;
  const int slot   = linear >> 3;
  const int bh     = (linear & 7) * 8 + (slot >> 4);
  const int i0     = (slot & 15) * 64;
  const int rbase  = w * 16 + quad * 4;

  // ---- Q A-fragments, pre-scaled by 0.125*log2(e) so exp2 args are bare adds
  bf16x8 aq[2];
  {
    const float* qp = Qf + (size_t)((bh * MQ + i0 + w * 16 + li) * DH) + quad * 8;
#pragma unroll
    for (int ks = 0; ks < 2; ++ks) {
      float4 f0 = *(const float4*)(qp + ks * 32);
      float4 f1 = *(const float4*)(qp + ks * 32 + 4);
      f0.x *= SCL_LOG2E; f0.y *= SCL_LOG2E; f0.z *= SCL_LOG2E; f0.w *= SCL_LOG2E;
      f1.x *= SCL_LOG2E; f1.y *= SCL_LOG2E; f1.z *= SCL_LOG2E; f1.w *= SCL_LOG2E;
      aq[ks] = mk8(pk2(f0.x, f0.y), pk2(f0.z, f0.w), pk2(f1.x, f1.y), pk2(f1.z, f1.w));
    }
  }

  float l_i[4] = {0.f, 0.f, 0.f, 0.f};
  f32x4 acco[4];
#pragma unroll
  for (int nt = 0; nt < 4; ++nt) acco[nt] = (f32x4){0.f, 0.f, 0.f, 0.f};

  f32x4 curPw[4];   // P over rel cols (4t-w+m)*16.., m=0..3 (per-wave window)
  f32x4 prevw3 = (f32x4){0.f, 0.f, 0.f, 0.f};

  for (int t = 0; t < NTILE; ++t) {
    const int j0 = i0 + t * 64;
    __syncthreads();   // protect sK/sV/sPE vs previous iteration's readers

    if constexpr (PRECONV) {
      {  // K tile: 8KB linear copy (pre-swizzled rows)
        const char* gb = (const char*)(Kb + ((size_t)bh * NKEY + j0) * 64);
#pragma unroll
        for (int it = 0; it < 2; ++it) {
          const int c0 = w * 128 + it * 64;
          async_copy16(gb + (size_t)(c0 + lane) * 16, (char*)sK + (size_t)c0 * 16);
        }
      }
      if (t < NTILE - 1) {  // PE block t -> circular slot t&1
        const char* gb = (const char*)(peT + (size_t)t * 64 * 64);
        char* db = (char*)sPE + (size_t)(t & 1) * 8192;
#pragma unroll
        for (int it = 0; it < 2; ++it) {
          const int c0 = w * 128 + it * 64;
          async_copy16(gb + (size_t)(c0 + lane) * 16, db + (size_t)c0 * 16);
        }
      }
      {  // V tile: gather from kappa-permuted V^T rows; swizzle via source granule
#pragma unroll
        for (int it = 0; it < 2; ++it) {
          const int s = w * 128 + it * 64 + lane;        // slot 0..511
          const int d = s >> 3;
          const int g = (s & 7) ^ (d & 7);               // logical kappa-granule
          const short* gp = Vb + ((size_t)bh * DH + d) * NKEY + j0 + g * 8;
          async_copy16(gp, (char*)sV + (size_t)(w * 128 + it * 64) * 16);
        }
      }
    } else {
      // ---- fallback: stage with in-kernel f32->bf16 conversion
      {
        const int srow = tid >> 2, l0 = tid & 3, sdb = l0 * 16;
        const float* src = Kf + (size_t)(bh * NKEY + j0 + srow) * DH + sdb;
        const float4 a0 = *(const float4*)(src + 0);
        const float4 a1 = *(const float4*)(src + 4);
        const float4 a2 = *(const float4*)(src + 8);
        const float4 a3 = *(const float4*)(src + 12);
        const bf16x8 b0 = mk8(pk2(a0.x, a0.y), pk2(a0.z, a0.w), pk2(a1.x, a1.y), pk2(a1.z, a1.w));
        const bf16x8 b1 = mk8(pk2(a2.x, a2.y), pk2(a2.z, a2.w), pk2(a3.x, a3.y), pk2(a3.z, a3.w));
        const int s7 = srow & 7;
        *(bf16x8*)&sK[srow * 64 + (((2 * l0)     ^ s7) * 8)] = b0;
        *(bf16x8*)&sK[srow * 64 + (((2 * l0 + 1) ^ s7) * 8)] = b1;
      }
      {
        const int vdb = (tid & 15) * 4, vkb = (tid >> 4) * 4;
        const float* src = Vf + (size_t)(bh * NKEY + j0 + vkb) * DH + vdb;
#pragma unroll
        for (int m = 0; m < 4; ++m) {             // key vkb+m
          const float4 rr = *(const float4*)(src + m * DH);
          const int k   = vkb + m;
          const int kap = (k & 15) * 4 + (k >> 4);
#pragma unroll
          for (int jj = 0; jj < 4; ++jj) {
            const int d = vdb + jj;
            const float fv = (jj == 0) ? rr.x : (jj == 1) ? rr.y : (jj == 2) ? rr.z : rr.w;
            sV[d * 64 + (((kap >> 3) ^ (d & 7)) * 8) + (kap & 7)] = f2bf(fv);
          }
        }
      }
      if (t < NTILE - 1) {
        const short* src = peT + (size_t)t * 64 * 64;   // already swizzled
        short* db = sPE + (size_t)(t & 1) * 4096;
        *(bf16x8*)&db[tid * 16]     = *(const bf16x8*)(src + tid * 16);
        *(bf16x8*)&db[tid * 16 + 8] = *(const bf16x8*)(src + tid * 16 + 8);
      }
    }
    __syncthreads();

    // ---- curPw[m] = Q @ PE over rel col (4t-w+m)*16..+15 (per-wave window).
    // Out-of-range cols read defined-but-stale LDS; killed by the band mask.
#pragma unroll
    for (int m = 0; m < 4; ++m) {
      const int colIdx = 4 * t - w + m;
      const int base = ((colIdx >> 2) & 1) * 4096 + ((colIdx & 3) * 16 + li) * 64;
      f32x4 c = (f32x4){0.f, 0.f, 0.f, 0.f};
#pragma unroll
      for (int ks = 0; ks < 2; ++ks) {
        const int gs = (((ks * 4 + quad) ^ (li & 7)) * 8);
        const bf16x8 b = *(bf16x8*)&sPE[base + gs];
        c = __builtin_amdgcn_mfma_f32_16x16x32_bf16(aq[ks], b, c, 0, 0, 0);
      }
      curPw[m] = c;
    }

    // ---- S = Q @ K^T (Q pre-scaled, so cs is already in log2-units)
    f32x4 cs[4];
#pragma unroll
    for (int nt = 0; nt < 4; ++nt) {
      f32x4 c = (f32x4){0.f, 0.f, 0.f, 0.f};
#pragma unroll
      for (int ks = 0; ks < 2; ++ks) {
        const int gs = (((ks * 4 + quad) ^ (li & 7)) * 8);
        const bf16x8 b = *(bf16x8*)&sK[(nt * 16 + li) * 64 + gs];
        c = __builtin_amdgcn_mfma_f32_16x16x32_bf16(aq[ks], b, c, 0, 0, 0);
      }
      cs[nt] = c;
    }

    // ---- diagonal gather (3 packed shuffles per r) + no-max softmax
    // dl = (nt-w)*16 + e, e = li - quad*4 - r.  pos(nt) = ge ? cur[nt]
    // : (nt ? cur[nt-1] : prevw3).  cur pairs travel as bf16x2.
#pragma unroll
    for (int r = 0; r < 4; ++r) {
      const int e       = li - quad * 4 - r;          // in [-15, 15]
      const bool ge     = (e >= 0);
      const int srcLane = quad * 16 + (e & 15);
      const float shm = __shfl(prevw3[r], srcLane);
      const unsigned pk01 = pk2(curPw[0][r], curPw[1][r]);
      const unsigned pk23 = pk2(curPw[2][r], curPw[3][r]);
      const unsigned s01 = (unsigned)__shfl((int)pk01, srcLane);
      const unsigned s23 = (unsigned)__shfl((int)pk23, srcLane);
      const float sh0 = bf2f((short)(s01 & 0xffffu));
      const float sh1 = bf2f((short)(s01 >> 16));
      const float sh2 = bf2f((short)(s23 & 0xffffu));
      const float sh3 = bf2f((short)(s23 >> 16));
      const float pos0 = ge ? sh0 : shm;
      const float pos1 = ge ? sh1 : sh0;
      const float pos2 = ge ? sh2 : sh1;
      const float pos3 = ge ? sh3 : sh2;
      float p0 = fast_exp2(cs[0][r] + pos0);
      float p1 = fast_exp2(cs[1][r] + pos1);
      float p2 = fast_exp2(cs[2][r] + pos2);
      float p3 = fast_exp2(cs[3][r] + pos3);
      if (t == 0) {                 // valid iff dl>=0: nt>w || (nt==w && ge)
        p0 = (0 > w || (0 == w && ge)) ? p0 : 0.f;
        p1 = (1 > w || (1 == w && ge)) ? p1 : 0.f;
        p2 = (2 > w || (2 == w && ge)) ? p2 : 0.f;
        p3 = (3 > w || (3 == w && ge)) ? p3 : 0.f;
      } else if (t == NTILE - 1) {  // valid iff dl<0: nt<w || (nt==w && !ge)
        p0 = (0 < w || (0 == w && !ge)) ? p0 : 0.f;
        p1 = (1 < w || (1 == w && !ge)) ? p1 : 0.f;
        p2 = (2 < w || (2 == w && !ge)) ? p2 : 0.f;
        p3 = (3 < w || (3 == w && !ge)) ? p3 : 0.f;
      }
      l_i[r] += (p0 + p1) + (p2 + p3);
      // kappa-order store: lane li's keys nt*16+li -> kappa = 4*li + nt,
      // contiguous => one b64. Granule (li>>1) ^ (rowA&7), offset (li&1)*4.
      const int rowA = rbase + r;
      const bf16x4 pkv = mk4(pk2(p0, p1), pk2(p2, p3));
      *(bf16x4*)&sPA[rowA * 64 + (((li >> 1) ^ (rowA & 7)) * 8) + (li & 1) * 4] = pkv;
    }
    prevw3 = curPw[3];

    // ---- O += P @ V  (kappa-ordered contraction on both operands)
#pragma unroll
    for (int ks = 0; ks < 2; ++ks) {
      const int rowA = w * 16 + li;
      const bf16x8 ap =
          *(bf16x8*)&sPA[rowA * 64 + (((ks * 4 + quad) ^ (rowA & 7)) * 8)];
#pragma unroll
      for (int nt = 0; nt < 4; ++nt) {
        const int d  = nt * 16 + li;
        const int gs = (((ks * 4 + quad) ^ (d & 7)) * 8);
        const bf16x8 bv = *(bf16x8*)&sV[d * 64 + gs];
        acco[nt] = __builtin_amdgcn_mfma_f32_16x16x32_bf16(ap, bv, acco[nt], 0, 0, 0);
      }
    }
  }

  // ---- epilogue: reduce l across the 16 lanes holding each row, out = O / l
#pragma unroll
  for (int r = 0; r < 4; ++r) {
    float l = l_i[r];
    l += __shfl_xor(l, 1);
    l += __shfl_xor(l, 2);
    l += __shfl_xor(l, 4);
    l += __shfl_xor(l, 8);
    const float inv = 1.0f / l;
#pragma unroll
    for (int nt = 0; nt < 4; ++nt) {
      Out[(size_t)(bh * MQ + i0 + rbase + r) * DH + nt * 16 + li] = acco[nt][r] * inv;
    }
  }
}

extern "C" void kernel_launch(void* const* d_in, const int* in_sizes, int n_in,
                              void* d_out, int out_size, void* d_ws, size_t ws_size,
                              hipStream_t stream) {
  const float* q  = (const float*)d_in[0];  // [64,1024,64]
  const float* k  = (const float*)d_in[1];  // [64,2048,64]
  const float* v  = (const float*)d_in[2];  // [64,2048,64]
  const float* pe = (const float*)d_in[3];  // [1,64,1024]
  float* out = (float*)d_out;               // [64,1024,64] f32
  short* peT = (short*)d_ws;
  short* Kb  = (short*)((char*)d_ws + OFF_K);
  short* Vb  = (short*)((char*)d_ws + OFF_V);
  const bool preconv = ws_size >= WS_NEED;  // constant across calls: capture-safe

  dim3 grid(MQ / 64, BHN);
  if (preconv) {
    prep_fused<<<4352, 256, 0, stream>>>(pe, k, v, peT, Kb, Vb);
    seq_attn_kernel<true><<<grid, 256, 0, stream>>>(q, k, v, peT, Kb, Vb, out);
  } else {
    prep_fused<<<256, 256, 0, stream>>>(pe, k, v, peT, Kb, Vb);
    seq_attn_kernel<false><<<grid, 256, 0, stream>>>(q, k, v, peT, Kb, Vb, out);
  }
}